// Round 12
// baseline (144.556 us; speedup 1.0000x reference)
//
#include <hip/hip_runtime.h>
#include <hip/hip_bf16.h>

#define ZD 64
#define HD 512
#define NB 256
#define KS 8
#define DIN 49152
#define DN 16384

typedef __attribute__((ext_vector_type(8))) short bf16x8;
typedef __attribute__((ext_vector_type(4))) float f32x4;

__device__ __forceinline__ ushort bfc(float x) {
  uint u = __float_as_uint(x);
  uint r = (u + 0x7FFFu + ((u >> 16) & 1u)) >> 16;
  return (ushort)r;
}
__device__ __forceinline__ uint pk2(float a, float b) {
  return (uint)bfc(a) | ((uint)bfc(b) << 16);
}
// HW packed f32->bf16 RTNE (T12 recipe; no builtin on gfx950)
__device__ __forceinline__ uint cvtpk(float lo, float hi) {
  uint r;
  asm("v_cvt_pk_bf16_f32 %0, %1, %2" : "=v"(r) : "v"(lo), "v"(hi));
  return r;
}
__device__ __forceinline__ float lof(uint u) { return __uint_as_float(u << 16); }
__device__ __forceinline__ float hif(uint u) { return __uint_as_float(u & 0xFFFF0000u); }
__device__ __forceinline__ float softplusf_(float x) {
  return fmaxf(x, 0.f) + log1pf(expf(-fabsf(x)));
}
__device__ __forceinline__ float softplus_fast(float x) {
  float e = __expf(-fabsf(x));
  return fmaxf(x, 0.f) + __logf(1.f + e);
}
__device__ __forceinline__ float sigmoidf_(float x) {
  return 1.f / (1.f + expf(-x));
}

// ---------------- Stem GEMM stage 1: partials[sp][b][h] ----------------
// BM=256 (W read ONCE), BN=128, BKK=32 (24 K-steps), SPLITS=64, grid 256 blocks.
// Block-id decode keeps the 4 nt-partners sharing an x-chunk on the SAME XCD.
#define SPLITS 64
#define KCH (DIN / SPLITS) /* 768 */
#define BKK 32

__global__ __launch_bounds__(256, 2)
void stem_kernel(const float* __restrict__ x, const float* __restrict__ W,
                 float* __restrict__ part) {
  __shared__ float Af[256 * 32];  // 32 KB f32 [row][slot16], slot16 = logical ^ (row&7)
  __shared__ uint Bt[128 * 20];   // 10 KB [n][16 u32 + 4 pad], granule-rotated
  const int id = blockIdx.x;                       // 0..255
  const int nt = (id >> 3) & 3;                    // n-tile 0..3
  const int sp = (id >> 5) * 8 + (id & 7);         // 0..63 (bijective)
  const int n0 = nt * 128;
  const int tid = threadIdx.x;
  const int lane = tid & 63;
  const int wave = tid >> 6;                 // 4 waves
  const int wm = wave >> 1, wn = wave & 1;   // wave tile: 128 x 64
  const int rr = lane & 15, gq = lane >> 4;

  f32x4 accr[8][4];
#pragma unroll
  for (int i = 0; i < 8; ++i)
#pragma unroll
    for (int j = 0; j < 4; ++j) accr[i][j] = (f32x4){0.f, 0.f, 0.f, 0.f};

  const int arow_b = tid >> 3;   // A: 8 thr/row; + 32*i per instr
  const int asub = tid & 7;      // 16B slot within 128B row-chunk
  const int bkq = tid >> 5, bn4 = tid & 31;  // B: k-quad, n-quad
  auto* ldsA = (__attribute__((address_space(3))) uint*)Af;

#pragma unroll 1
  for (int it = 0; it < KCH / BKK; ++it) {
    const int k0 = sp * KCH + it * BKK;
    __syncthreads();  // previous compute done; LDS safe to overwrite
    // ---- A: 8x global_load_lds(16B). LDS dest linear; global k-slot pre-XOR'd
    //      (rule #21: same involution on source and read side).
#pragma unroll
    for (int i = 0; i < 8; ++i) {
      const int row = i * 32 + arow_b;
      const int slot = asub ^ (row & 7);
      const float* g = x + (size_t)row * DIN + k0 + slot * 4;
      __builtin_amdgcn_global_load_lds(
          (const __attribute__((address_space(1))) uint*)g,
          ldsA + i * 1024 + wave * 256, 16, 0, 0);
    }
    // ---- B: 4x float4 (batched), cvt_pk, transpose-write [n][k] rotated
    {
      float4 vb[4];
#pragma unroll
      for (int j = 0; j < 4; ++j)
        vb[j] = *(const float4*)(W + (size_t)(k0 + bkq * 4 + j) * HD + n0 + bn4 * 4);
      const int gg = bkq >> 1, sb = bkq & 1;
#pragma unroll
      for (int c = 0; c < 4; ++c) {
        const int n = bn4 * 4 + c;
        const float* q0 = (const float*)&vb[0];
        const float* q1 = (const float*)&vb[1];
        const float* q2 = (const float*)&vb[2];
        const float* q3 = (const float*)&vb[3];
        uint lo = cvtpk(q0[c], q1[c]);
        uint hi = cvtpk(q2[c], q3[c]);
        const int rot = (gg + (n >> 2) + n) & 3;
        *(uint2*)&Bt[n * 20 + rot * 4 + sb * 2] = make_uint2(lo, hi);
      }
    }
    asm volatile("s_waitcnt vmcnt(0)" ::: "memory");
    __syncthreads();  // all staging (gload_lds + ds_writes) visible
    // ---- compute: fragments from LDS, convert A on the fly, 32 MFMA
    bf16x8 af[8], bfr[4];
#pragma unroll
    for (int mf = 0; mf < 8; ++mf) {
      const int r = wm * 128 + mf * 16 + rr;
      const int s = r & 7;
      float4 a0 = *(const float4*)&Af[r * 32 + ((gq * 2) ^ s) * 4];
      float4 a1 = *(const float4*)&Af[r * 32 + ((gq * 2 + 1) ^ s) * 4];
      uint4 au = make_uint4(cvtpk(a0.x, a0.y), cvtpk(a0.z, a0.w),
                            cvtpk(a1.x, a1.y), cvtpk(a1.z, a1.w));
      af[mf] = *(bf16x8*)&au;
    }
#pragma unroll
    for (int nf = 0; nf < 4; ++nf) {
      const int n = wn * 64 + nf * 16 + rr;
      const int rot = (gq + (n >> 2) + n) & 3;
      uint4 bu = *(const uint4*)&Bt[n * 20 + rot * 4];
      bfr[nf] = *(bf16x8*)&bu;
    }
#pragma unroll
    for (int mf = 0; mf < 8; ++mf)
#pragma unroll
      for (int nf = 0; nf < 4; ++nf)
        accr[mf][nf] = __builtin_amdgcn_mfma_f32_16x16x32_bf16(
            af[mf], bfr[nf], accr[mf][nf], 0, 0, 0);
  }

  // C/D layout: col = lane&15, row = 4*(lane>>4)+i ; plain coalesced stores
  const int ccol = lane & 15, crow = (lane >> 4) * 4;
  float* base = part + (size_t)sp * (NB * HD);
#pragma unroll
  for (int mf = 0; mf < 8; ++mf) {
#pragma unroll
    for (int nf = 0; nf < 4; ++nf) {
      const int col = n0 + wn * 64 + nf * 16 + ccol;
      const int row = wm * 128 + mf * 16 + crow;
#pragma unroll
      for (int i = 0; i < 4; ++i)
        base[(size_t)(row + i) * HD + col] = accr[mf][nf][i];
    }
  }
}

// ---- Stem stage 2: acc = sum over 64 splits; 2 threads/output to halve latency ----
__global__ __launch_bounds__(256)
void reduce_kernel(const float* __restrict__ part, float* __restrict__ acc) {
  __shared__ float4 sh[128];
  const int f4 = blockIdx.x * 128 + (threadIdx.x & 127);  // 32768 float4 outputs
  const int half = threadIdx.x >> 7;                      // 0 or 1
  const float4* p = (const float4*)part;
  float4 s = {0.f, 0.f, 0.f, 0.f};
#pragma unroll 8
  for (int sp = half * 32; sp < half * 32 + 32; ++sp) {
    float4 v = p[(size_t)sp * (NB * HD / 4) + f4];
    s.x += v.x; s.y += v.y; s.z += v.z; s.w += v.w;
  }
  if (half) sh[threadIdx.x - 128] = s;
  __syncthreads();
  if (!half) {
    float4 o = sh[threadIdx.x];
    o.x += s.x; o.y += s.y; o.z += s.z; o.w += s.w;
    ((float4*)acc)[f4] = o;
  }
}

// ---- prep: WdT transpose + WcombT + scan-weight bf16 packing, one launch ----
// bx<64: WdT ; 64<=bx<144: WcombT ; 144<=bx<160: pack wzq/wzp/wlq/wlp
__global__ __launch_bounds__(256)
void prep_kernel(const float* __restrict__ Wd, ushort* __restrict__ WdT,
                 const float* __restrict__ Wihq, const float* __restrict__ Wg,
                 ushort* __restrict__ WcT,
                 const float* __restrict__ Wihp,
                 const float* __restrict__ Wlinq, const float* __restrict__ Wlinp,
                 uint* __restrict__ wzq, uint* __restrict__ wzp,
                 uint* __restrict__ wlq, uint* __restrict__ wlp) {
  __shared__ float T[64][68];
  const int bx = blockIdx.x;
  const int t = threadIdx.x;
  if (bx < 64) {  // WdT[col*64+k] = bf16(Wd[k*DN+col])
    const int c = bx * 256 + t;
    uint packed[32];
#pragma unroll
    for (int k = 0; k < 32; ++k) {
      float a = Wd[(size_t)(2 * k) * DN + c];
      float b = Wd[(size_t)(2 * k + 1) * DN + c];
      packed[k] = pk2(a, b);
    }
    uint4* dst = (uint4*)&WdT[(size_t)c * 64];
#pragma unroll
    for (int i = 0; i < 8; ++i)
      dst[i] = make_uint4(packed[4 * i], packed[4 * i + 1], packed[4 * i + 2],
                          packed[4 * i + 3]);
  } else if (bx < 144) {  // WcombT: bf16 [640 cols][512 k] of [Wihq[:512] | Wg]
    const int bx2 = bx - 64;
    const int cx = bx2 % 10, ky = bx2 / 10;
    const int ct = cx * 64, kt = ky * 64;
    {
      const int rl = t >> 2, cq = (t & 3) * 16;
      const float* src = (cx < 8) ? &Wihq[(size_t)(kt + rl) * 512 + ct + cq]
                                  : &Wg[(size_t)(kt + rl) * 128 + (ct - 512) + cq];
#pragma unroll
      for (int i = 0; i < 4; ++i) {
        float4 v = *(const float4*)(src + 4 * i);
        T[rl][cq + 4 * i + 0] = v.x;
        T[rl][cq + 4 * i + 1] = v.y;
        T[rl][cq + 4 * i + 2] = v.z;
        T[rl][cq + 4 * i + 3] = v.w;
      }
    }
    __syncthreads();
    {
      const int cl = t >> 2, kq = (t & 3) * 16;
      uint* dst = (uint*)WcT;
#pragma unroll
      for (int i = 0; i < 8; ++i) {
        uint u = pk2(T[kq + 2 * i][cl], T[kq + 2 * i + 1][cl]);
        dst[(((size_t)(ct + cl)) * 512 + kt + kq + 2 * i) >> 1] = u;
      }
    }
  } else {  // pack scan weights to bf16 pairs
    const int tp = (bx - 144) * 256 + t;  // 0..4095
#pragma unroll
    for (int r2 = 0; r2 < 4; ++r2) {
      const int i = tp * 4 + r2;          // 0..16383
      const int zp = i >> 9, col = i & 511;
      wzq[i] = pk2(Wihq[(size_t)(HD + 2 * zp) * HD + col],
                   Wihq[(size_t)(HD + 2 * zp + 1) * HD + col]);
      wzp[i] = pk2(Wihp[(size_t)(2 * zp) * HD + col],
                   Wihp[(size_t)(2 * zp + 1) * HD + col]);
      if (i < 8192) {
        const int kp2 = i >> 7, jj = i & 127;
        wlq[i] = pk2(Wlinq[(2 * kp2) * 128 + jj], Wlinq[(2 * kp2 + 1) * 128 + jj]);
        wlp[i] = pk2(Wlinp[(2 * kp2) * 128 + jj], Wlinp[(2 * kp2 + 1) * 128 + jj]);
      }
    }
  }
}

// ---- gemmA: hf = relu(acc+bstem); hfqg = hf@Wihq[:512]+bq ; enc0g = hf@Wg+bg ----
__global__ __launch_bounds__(256)
void gemmA_kernel(const float* __restrict__ acc, const float* __restrict__ bstem,
                  const ushort* __restrict__ WcT, const float* __restrict__ bq,
                  const float* __restrict__ bg, float* __restrict__ hfqg,
                  float* __restrict__ enc0g) {
  const int tid = threadIdx.x;
  const int lane = tid & 63;
  const int wave = tid >> 6;
  const int rr = lane & 15, gq = lane >> 4;
  const int mtile = blockIdx.y * 16;
  const int ncol = blockIdx.x * 64 + wave * 16;
  const int row = mtile + rr;

  f32x4 a4 = (f32x4){0.f, 0.f, 0.f, 0.f};
#pragma unroll
  for (int ks2 = 0; ks2 < 16; ++ks2) {
    const int k0 = ks2 * 32 + gq * 8;
    float4 x0 = *(const float4*)&acc[(size_t)row * HD + k0];
    float4 x1 = *(const float4*)&acc[(size_t)row * HD + k0 + 4];
    float4 b0 = *(const float4*)&bstem[k0];
    float4 b1 = *(const float4*)&bstem[k0 + 4];
    bf16x8 af;
    af[0] = (short)bfc(fmaxf(x0.x + b0.x, 0.f));
    af[1] = (short)bfc(fmaxf(x0.y + b0.y, 0.f));
    af[2] = (short)bfc(fmaxf(x0.z + b0.z, 0.f));
    af[3] = (short)bfc(fmaxf(x0.w + b0.w, 0.f));
    af[4] = (short)bfc(fmaxf(x1.x + b1.x, 0.f));
    af[5] = (short)bfc(fmaxf(x1.y + b1.y, 0.f));
    af[6] = (short)bfc(fmaxf(x1.z + b1.z, 0.f));
    af[7] = (short)bfc(fmaxf(x1.w + b1.w, 0.f));
    bf16x8 bf = *(const bf16x8*)&WcT[(size_t)(ncol + rr) * 512 + k0];
    a4 = __builtin_amdgcn_mfma_f32_16x16x32_bf16(af, bf, a4, 0, 0, 0);
  }
  const int col = ncol + rr;
  if (col < 512) {
    const float bb = bq[col];
#pragma unroll
    for (int i = 0; i < 4; ++i)
      hfqg[(size_t)(mtile + 4 * gq + i) * HD + col] = a4[i] + bb;
  } else {
    const float bb = bg[col - 512];
#pragma unroll
    for (int i = 0; i < 4; ++i)
      enc0g[(size_t)(mtile + 4 * gq + i) * 128 + (col - 512)] = a4[i] + bb;
  }
}

// ---------------- Recurrent scan: one block (512 thr) per batch row ----------------
// Reads PRE-PACKED bf16 weights (halves global traffic vs f32 + packing in-kernel).
__global__ __launch_bounds__(512, 2)
void scan_kernel(const float* __restrict__ hfqg, const float* __restrict__ enc0g,
                 const uint* __restrict__ wzqg, const uint* __restrict__ wzpg,
                 const uint* __restrict__ wlqg, const uint* __restrict__ wlpg,
                 const float* __restrict__ blinq, const float* __restrict__ blinp,
                 const float* __restrict__ bp,
                 const float* __restrict__ eps0, const float* __restrict__ epsq,
                 ushort* __restrict__ zsb, float* __restrict__ out_kl) {
  const int b = blockIdx.x, tid = threadIdx.x;
  __shared__ uint WlL[2][64 * 128];
  __shared__ float g[512], gp[512];
  __shared__ float hq[128], hp[128];
  __shared__ float psum[512];
  __shared__ float zsh[64];
  __shared__ float epsL[448];

  uint wq[32], wp[32];
#pragma unroll
  for (int zp = 0; zp < 32; ++zp) {
    wq[zp] = wzqg[zp * 512 + tid];
    wp[zp] = wzpg[zp * 512 + tid];
  }
#pragma unroll
  for (int i = 0; i < 16; ++i) {
    const int idx = i * 512 + tid;
    WlL[0][idx] = wlqg[idx];
    WlL[1][idx] = wlpg[idx];
  }
  if (tid < 448) epsL[tid] = epsq[(size_t)((tid >> 6) * NB + b) * ZD + (tid & 63)];
  const float hfq_reg = hfqg[(size_t)b * HD + tid];
  const float bp_reg = bp[tid];
  if (tid < 64) {
    float mu = enc0g[b * 128 + tid], lv = enc0g[b * 128 + 64 + tid];
    float s0 = softplusf_(lv + 0.5f) + 1e-8f;
    float z0 = mu + s0 * eps0[b * ZD + tid];
    zsh[tid] = z0;
    zsb[(b * KS) * ZD + tid] = bfc(z0);
    out_kl[(b * ZD + tid) * KS] = -logf(s0) + (s0 * s0 + mu * mu) * 0.5f - 0.5f;
  }
  __syncthreads();

  for (int t = 0; t < KS - 1; ++t) {
    float aq = hfq_reg, ap = bp_reg;
#pragma unroll
    for (int zp = 0; zp < 32; ++zp) {
      float z0v = zsh[2 * zp], z1v = zsh[2 * zp + 1];
      uint uq = wq[zp], up = wp[zp];
      aq += z0v * lof(uq) + z1v * hif(uq);
      ap += z0v * lof(up) + z1v * hif(up);
    }
    g[tid] = aq;
    gp[tid] = ap;
    __syncthreads();
    if (tid < 128) {
      float cs = sigmoidf_(g[tid]) * tanhf(g[256 + tid]);
      hq[tid] = sigmoidf_(g[384 + tid]) * tanhf(cs);
    } else if (tid < 256) {
      int j = tid & 127;
      float cs = sigmoidf_(gp[j]) * tanhf(gp[256 + j]);
      hp[j] = sigmoidf_(gp[384 + j]) * tanhf(cs);
    }
    __syncthreads();
    {
      int s = tid & 255, jj = s & 127, kc = s >> 7;
      int mq_ = tid >> 8;
      const float* h = mq_ ? hp : hq;
      const uint* W = WlL[mq_];
      float a = 0.f;
#pragma unroll
      for (int kp = 0; kp < 32; ++kp) {
        uint u = W[(kc * 32 + kp) * 128 + jj];
        a += h[kc * 64 + 2 * kp] * lof(u) + h[kc * 64 + 2 * kp + 1] * hif(u);
      }
      psum[tid] = a;
    }
    __syncthreads();
    if (tid < 64) {
      float mq = psum[tid] + psum[128 + tid] + blinq[tid];
      float lq = psum[64 + tid] + psum[192 + tid] + blinq[64 + tid];
      float sq = softplusf_(lq + 0.5f) + 1e-8f;
      float zq = mq + sq * epsL[t * 64 + tid];
      float mp2 = psum[256 + tid] + psum[384 + tid] + blinp[tid];
      float lp = psum[320 + tid] + psum[448 + tid] + blinp[64 + tid];
      float sp_ = softplusf_(lp + 0.5f) + 1e-8f;
      float d = mq - mp2;
      out_kl[(b * ZD + tid) * KS + t + 1] =
          logf(sp_ / sq) + (sq * sq + d * d) / (2.f * sp_ * sp_) - 0.5f;
      zsb[(b * KS + t + 1) * ZD + tid] = bfc(zq);
      zsh[tid] = zq;
    }
    __syncthreads();
  }
}

// -------- Decoder: MFMA + log-sigmoid + excl k-cumsum. 2 m-tiles/block, ILP-hoisted --------
__global__ __launch_bounds__(256)
void dec_kernel(const ushort* __restrict__ zsb, const ushort* __restrict__ WdT,
                const float* __restrict__ bd, float* __restrict__ out) {
  const int tid = threadIdx.x;
  const int lane = tid & 63;
  const int wave = tid >> 6;
  const int rr = lane & 15, gq = lane >> 4;
  const int mtile0 = blockIdx.y * 32;              // 2048/32 = 64
  const int ncol0 = blockIdx.x * 256 + wave * 64;  // 16384/256 = 64

  bf16x8 bfr[2][4];
#pragma unroll
  for (int ks2 = 0; ks2 < 2; ++ks2)
#pragma unroll
    for (int nf = 0; nf < 4; ++nf)
      bfr[ks2][nf] = *(const bf16x8*)&WdT[(size_t)(ncol0 + nf * 16 + rr) * 64 +
                                          ks2 * 32 + gq * 8];
  bf16x8 af[2][2];
#pragma unroll
  for (int mi = 0; mi < 2; ++mi)
#pragma unroll
    for (int ks2 = 0; ks2 < 2; ++ks2)
      af[mi][ks2] = *(const bf16x8*)&zsb[(size_t)(mtile0 + mi * 16 + rr) * 64 +
                                         ks2 * 32 + gq * 8];
  float bde[4];
#pragma unroll
  for (int nf = 0; nf < 4; ++nf) bde[nf] = bd[ncol0 + nf * 16 + rr];

  f32x4 acc[2][4];
#pragma unroll
  for (int mi = 0; mi < 2; ++mi)
#pragma unroll
    for (int nf = 0; nf < 4; ++nf) acc[mi][nf] = (f32x4){0.f, 0.f, 0.f, 0.f};

#pragma unroll
  for (int mi = 0; mi < 2; ++mi)
#pragma unroll
    for (int ks2 = 0; ks2 < 2; ++ks2)
#pragma unroll
      for (int nf = 0; nf < 4; ++nf)
        acc[mi][nf] = __builtin_amdgcn_mfma_f32_16x16x32_bf16(
            af[mi][ks2], bfr[ks2][nf], acc[mi][nf], 0, 0, 0);

  const int khi = (gq & 1) * 4;
#pragma unroll
  for (int mi = 0; mi < 2; ++mi) {
    const int bb = ((mtile0 + mi * 16) >> 3) + (gq >> 1);
#pragma unroll
    for (int nf = 0; nf < 4; ++nf) {
      const int col = ncol0 + nf * 16 + rr;
      float run = 0.f;
      float ov[4];
#pragma unroll
      for (int i = 0; i < 4; ++i) {
        float dec = acc[mi][nf][i] + bde[nf];
        float spd = softplus_fast(dec);
        ov[i] = run + (dec - spd);
        run -= spd;
      }
      float prev = __shfl_xor(run, 16, 64);
      float base = (gq & 1) ? prev : 0.f;
#pragma unroll
      for (int i = 0; i < 4; ++i)
        out[((size_t)(khi + i) * NB + bb) * DN + col] = ov[i] + base;
    }
  }
}

extern "C" void kernel_launch(void* const* d_in, const int* in_sizes, int n_in,
                              void* d_out, int out_size, void* d_ws, size_t ws_size,
                              hipStream_t stream) {
  (void)in_sizes; (void)n_in; (void)out_size; (void)ws_size;
  const float* x     = (const float*)d_in[0];
  const float* eps0  = (const float*)d_in[2];
  const float* epsq  = (const float*)d_in[3];
  const float* Wstem = (const float*)d_in[5];
  const float* bstem = (const float*)d_in[6];
  const float* Wg    = (const float*)d_in[7];
  const float* bgp   = (const float*)d_in[8];
  const float* Wihq  = (const float*)d_in[9];
  const float* bq    = (const float*)d_in[10];
  const float* Wlinq = (const float*)d_in[11];
  const float* blinq = (const float*)d_in[12];
  const float* Wihp  = (const float*)d_in[13];
  const float* bp    = (const float*)d_in[14];
  const float* Wlinp = (const float*)d_in[15];
  const float* blinp = (const float*)d_in[16];
  const float* Wd    = (const float*)d_in[17];
  const float* bd    = (const float*)d_in[18];

  float* out    = (float*)d_out;
  float* outkl  = out + (size_t)KS * NB * DN;
  float* accbuf = (float*)d_ws;                        // 512 KB
  ushort* zsb   = (ushort*)(accbuf + NB * HD);         // 256 KB
  ushort* wdt   = zsb + (size_t)KS * NB * ZD;          // 2 MB
  ushort* wcombT = wdt + (size_t)DN * ZD;              // 640 KB
  float* hfqg   = (float*)(wcombT + 640 * 512);        // 512 KB
  float* enc0g  = hfqg + NB * HD;                      // 128 KB
  uint* wzq     = (uint*)(enc0g + NB * 128);           // 64 KB
  uint* wzp     = wzq + 32 * 512;                      // 64 KB
  uint* wlq     = wzp + 32 * 512;                      // 32 KB
  uint* wlp     = wlq + 64 * 128;                      // 32 KB
  // split-K partials live in d_out's log_ms region (134 MB, dead until dec runs):
  float* part   = out;  // 64 * 256*512 f32 = 32 MB

  prep_kernel<<<160, 256, 0, stream>>>(Wd, wdt, Wihq, Wg, wcombT, Wihp,
                                       Wlinq, Wlinp, wzq, wzp, wlq, wlp);
  stem_kernel<<<4 * SPLITS, 256, 0, stream>>>(x, Wstem, part);
  reduce_kernel<<<NB * HD / 4 / 128, 256, 0, stream>>>(part, accbuf);
  gemmA_kernel<<<dim3(10, 16), 256, 0, stream>>>(accbuf, bstem, wcombT, bq, bgp,
                                                 hfqg, enc0g);
  scan_kernel<<<NB, 512, 0, stream>>>(hfqg, enc0g, wzq, wzp, wlq, wlp,
                                      blinq, blinp, bp, eps0, epsq, zsb, outkl);
  dec_kernel<<<dim3(64, 64), 256, 0, stream>>>(zsb, wdt, bd, out);
}

// Round 13
// 132.170 us; speedup vs baseline: 1.0937x; 1.0937x over previous
//
#include <hip/hip_runtime.h>
#include <hip/hip_bf16.h>

#define ZD 64
#define HD 512
#define NB 256
#define KS 8
#define DIN 49152
#define DN 16384

typedef __attribute__((ext_vector_type(8))) short bf16x8;
typedef __attribute__((ext_vector_type(4))) float f32x4;

__device__ __forceinline__ ushort bfc(float x) {
  uint u = __float_as_uint(x);
  uint r = (u + 0x7FFFu + ((u >> 16) & 1u)) >> 16;
  return (ushort)r;
}
__device__ __forceinline__ uint pk2(float a, float b) {
  return (uint)bfc(a) | ((uint)bfc(b) << 16);
}
// HW packed f32->bf16 RTNE (T12 recipe; no builtin on gfx950)
__device__ __forceinline__ uint cvtpk(float lo, float hi) {
  uint r;
  asm("v_cvt_pk_bf16_f32 %0, %1, %2" : "=v"(r) : "v"(lo), "v"(hi));
  return r;
}
__device__ __forceinline__ float lof(uint u) { return __uint_as_float(u << 16); }
__device__ __forceinline__ float hif(uint u) { return __uint_as_float(u & 0xFFFF0000u); }
__device__ __forceinline__ float softplusf_(float x) {
  return fmaxf(x, 0.f) + log1pf(expf(-fabsf(x)));
}
__device__ __forceinline__ float softplus_fast(float x) {
  float e = __expf(-fabsf(x));
  return fmaxf(x, 0.f) + __logf(1.f + e);
}
__device__ __forceinline__ float sigmoidf_(float x) {
  return 1.f / (1.f + expf(-x));
}

// ---------------- Stem GEMM stage 1: partials[sp][b][h] ----------------
// BM=256 (W read ONCE), BN=128, BKK=32 (12 K-steps), SPLITS=128, grid 512 blocks
// = 2 blocks/CU (R11-measured ~49us). Per-K-step convoy cost (~3.5us serial)
// overlaps across resident blocks -- SPLITS=64/1-block-CU was 83us (R12).
#define SPLITS 128
#define KCH (DIN / SPLITS) /* 384 */
#define BKK 32

__global__ __launch_bounds__(256, 2)
void stem_kernel(const float* __restrict__ x, const float* __restrict__ W,
                 float* __restrict__ part) {
  __shared__ float Af[256 * 32];  // 32 KB f32 [row][slot16], slot16 = logical ^ (row&7)
  __shared__ uint Bt[128 * 20];   // 10 KB [n][16 u32 + 4 pad], granule-rotated
  const int id = blockIdx.x;                       // 0..511
  const int nt = (id >> 3) & 3;                    // n-tile 0..3
  const int sp = (id >> 5) * 8 + (id & 7);         // 0..127 (bijective)
  const int n0 = nt * 128;
  const int tid = threadIdx.x;
  const int lane = tid & 63;
  const int wave = tid >> 6;                 // 4 waves
  const int wm = wave >> 1, wn = wave & 1;   // wave tile: 128 x 64
  const int rr = lane & 15, gq = lane >> 4;

  f32x4 accr[8][4];
#pragma unroll
  for (int i = 0; i < 8; ++i)
#pragma unroll
    for (int j = 0; j < 4; ++j) accr[i][j] = (f32x4){0.f, 0.f, 0.f, 0.f};

  const int arow_b = tid >> 3;   // A: 8 thr/row; + 32*i per instr
  const int asub = tid & 7;      // 16B slot within 128B row-chunk
  const int bkq = tid >> 5, bn4 = tid & 31;  // B: k-quad, n-quad
  auto* ldsA = (__attribute__((address_space(3))) uint*)Af;

#pragma unroll 1
  for (int it = 0; it < KCH / BKK; ++it) {
    const int k0 = sp * KCH + it * BKK;
    __syncthreads();  // previous compute done; LDS safe to overwrite
    // ---- A: 8x global_load_lds(16B). LDS dest linear; global k-slot pre-XOR'd
    //      (rule #21: same involution on source and read side).
#pragma unroll
    for (int i = 0; i < 8; ++i) {
      const int row = i * 32 + arow_b;
      const int slot = asub ^ (row & 7);
      const float* g = x + (size_t)row * DIN + k0 + slot * 4;
      __builtin_amdgcn_global_load_lds(
          (const __attribute__((address_space(1))) uint*)g,
          ldsA + i * 1024 + wave * 256, 16, 0, 0);
    }
    // ---- B: 4x float4 (batched), cvt_pk, transpose-write [n][k] rotated
    {
      float4 vb[4];
#pragma unroll
      for (int j = 0; j < 4; ++j)
        vb[j] = *(const float4*)(W + (size_t)(k0 + bkq * 4 + j) * HD + n0 + bn4 * 4);
      const int gg = bkq >> 1, sb = bkq & 1;
#pragma unroll
      for (int c = 0; c < 4; ++c) {
        const int n = bn4 * 4 + c;
        const float* q0 = (const float*)&vb[0];
        const float* q1 = (const float*)&vb[1];
        const float* q2 = (const float*)&vb[2];
        const float* q3 = (const float*)&vb[3];
        uint lo = cvtpk(q0[c], q1[c]);
        uint hi = cvtpk(q2[c], q3[c]);
        const int rot = (gg + (n >> 2) + n) & 3;
        *(uint2*)&Bt[n * 20 + rot * 4 + sb * 2] = make_uint2(lo, hi);
      }
    }
    asm volatile("s_waitcnt vmcnt(0)" ::: "memory");
    __syncthreads();  // all staging (gload_lds + ds_writes) visible
    // ---- compute: fragments from LDS, convert A on the fly, 32 MFMA
    bf16x8 af[8], bfr[4];
#pragma unroll
    for (int mf = 0; mf < 8; ++mf) {
      const int r = wm * 128 + mf * 16 + rr;
      const int s = r & 7;
      float4 a0 = *(const float4*)&Af[r * 32 + ((gq * 2) ^ s) * 4];
      float4 a1 = *(const float4*)&Af[r * 32 + ((gq * 2 + 1) ^ s) * 4];
      uint4 au = make_uint4(cvtpk(a0.x, a0.y), cvtpk(a0.z, a0.w),
                            cvtpk(a1.x, a1.y), cvtpk(a1.z, a1.w));
      af[mf] = *(bf16x8*)&au;
    }
#pragma unroll
    for (int nf = 0; nf < 4; ++nf) {
      const int n = wn * 64 + nf * 16 + rr;
      const int rot = (gq + (n >> 2) + n) & 3;
      uint4 bu = *(const uint4*)&Bt[n * 20 + rot * 4];
      bfr[nf] = *(bf16x8*)&bu;
    }
#pragma unroll
    for (int mf = 0; mf < 8; ++mf)
#pragma unroll
      for (int nf = 0; nf < 4; ++nf)
        accr[mf][nf] = __builtin_amdgcn_mfma_f32_16x16x32_bf16(
            af[mf], bfr[nf], accr[mf][nf], 0, 0, 0);
  }

  // C/D layout: col = lane&15, row = 4*(lane>>4)+i ; plain coalesced stores
  const int ccol = lane & 15, crow = (lane >> 4) * 4;
  float* base = part + (size_t)sp * (NB * HD);
#pragma unroll
  for (int mf = 0; mf < 8; ++mf) {
#pragma unroll
    for (int nf = 0; nf < 4; ++nf) {
      const int col = n0 + wn * 64 + nf * 16 + ccol;
      const int row = wm * 128 + mf * 16 + crow;
#pragma unroll
      for (int i = 0; i < 4; ++i)
        base[(size_t)(row + i) * HD + col] = accr[mf][nf][i];
    }
  }
}

// ---- Stem stage 2: acc = sum over 128 splits; 2 threads/output ----
__global__ __launch_bounds__(256)
void reduce_kernel(const float* __restrict__ part, float* __restrict__ acc) {
  __shared__ float4 sh[128];
  const int f4 = blockIdx.x * 128 + (threadIdx.x & 127);  // 32768 float4 outputs
  const int half = threadIdx.x >> 7;                      // 0 or 1
  const float4* p = (const float4*)part;
  float4 s = {0.f, 0.f, 0.f, 0.f};
#pragma unroll 8
  for (int sp = half * 64; sp < half * 64 + 64; ++sp) {
    float4 v = p[(size_t)sp * (NB * HD / 4) + f4];
    s.x += v.x; s.y += v.y; s.z += v.z; s.w += v.w;
  }
  if (half) sh[threadIdx.x - 128] = s;
  __syncthreads();
  if (!half) {
    float4 o = sh[threadIdx.x];
    o.x += s.x; o.y += s.y; o.z += s.z; o.w += s.w;
    ((float4*)acc)[f4] = o;
  }
}

// ---- prep: WdT transpose + WcombT + scan-weight bf16 packing, one launch ----
// bx<64: WdT ; 64<=bx<144: WcombT ; 144<=bx<160: pack wzq/wzp/wlq/wlp
__global__ __launch_bounds__(256)
void prep_kernel(const float* __restrict__ Wd, ushort* __restrict__ WdT,
                 const float* __restrict__ Wihq, const float* __restrict__ Wg,
                 ushort* __restrict__ WcT,
                 const float* __restrict__ Wihp,
                 const float* __restrict__ Wlinq, const float* __restrict__ Wlinp,
                 uint* __restrict__ wzq, uint* __restrict__ wzp,
                 uint* __restrict__ wlq, uint* __restrict__ wlp) {
  __shared__ float T[64][68];
  const int bx = blockIdx.x;
  const int t = threadIdx.x;
  if (bx < 64) {  // WdT[col*64+k] = bf16(Wd[k*DN+col])
    const int c = bx * 256 + t;
    uint packed[32];
#pragma unroll
    for (int k = 0; k < 32; ++k) {
      float a = Wd[(size_t)(2 * k) * DN + c];
      float b = Wd[(size_t)(2 * k + 1) * DN + c];
      packed[k] = pk2(a, b);
    }
    uint4* dst = (uint4*)&WdT[(size_t)c * 64];
#pragma unroll
    for (int i = 0; i < 8; ++i)
      dst[i] = make_uint4(packed[4 * i], packed[4 * i + 1], packed[4 * i + 2],
                          packed[4 * i + 3]);
  } else if (bx < 144) {  // WcombT: bf16 [640 cols][512 k] of [Wihq[:512] | Wg]
    const int bx2 = bx - 64;
    const int cx = bx2 % 10, ky = bx2 / 10;
    const int ct = cx * 64, kt = ky * 64;
    {
      const int rl = t >> 2, cq = (t & 3) * 16;
      const float* src = (cx < 8) ? &Wihq[(size_t)(kt + rl) * 512 + ct + cq]
                                  : &Wg[(size_t)(kt + rl) * 128 + (ct - 512) + cq];
#pragma unroll
      for (int i = 0; i < 4; ++i) {
        float4 v = *(const float4*)(src + 4 * i);
        T[rl][cq + 4 * i + 0] = v.x;
        T[rl][cq + 4 * i + 1] = v.y;
        T[rl][cq + 4 * i + 2] = v.z;
        T[rl][cq + 4 * i + 3] = v.w;
      }
    }
    __syncthreads();
    {
      const int cl = t >> 2, kq = (t & 3) * 16;
      uint* dst = (uint*)WcT;
#pragma unroll
      for (int i = 0; i < 8; ++i) {
        uint u = pk2(T[kq + 2 * i][cl], T[kq + 2 * i + 1][cl]);
        dst[(((size_t)(ct + cl)) * 512 + kt + kq + 2 * i) >> 1] = u;
      }
    }
  } else {  // pack scan weights to bf16 pairs
    const int tp = (bx - 144) * 256 + t;  // 0..4095
#pragma unroll
    for (int r2 = 0; r2 < 4; ++r2) {
      const int i = tp * 4 + r2;          // 0..16383
      const int zp = i >> 9, col = i & 511;
      wzq[i] = pk2(Wihq[(size_t)(HD + 2 * zp) * HD + col],
                   Wihq[(size_t)(HD + 2 * zp + 1) * HD + col]);
      wzp[i] = pk2(Wihp[(size_t)(2 * zp) * HD + col],
                   Wihp[(size_t)(2 * zp + 1) * HD + col]);
      if (i < 8192) {
        const int kp2 = i >> 7, jj = i & 127;
        wlq[i] = pk2(Wlinq[(2 * kp2) * 128 + jj], Wlinq[(2 * kp2 + 1) * 128 + jj]);
        wlp[i] = pk2(Wlinp[(2 * kp2) * 128 + jj], Wlinp[(2 * kp2 + 1) * 128 + jj]);
      }
    }
  }
}

// ---- gemmA: hf = relu(acc+bstem); hfqg = hf@Wihq[:512]+bq ; enc0g = hf@Wg+bg ----
__global__ __launch_bounds__(256)
void gemmA_kernel(const float* __restrict__ acc, const float* __restrict__ bstem,
                  const ushort* __restrict__ WcT, const float* __restrict__ bq,
                  const float* __restrict__ bg, float* __restrict__ hfqg,
                  float* __restrict__ enc0g) {
  const int tid = threadIdx.x;
  const int lane = tid & 63;
  const int wave = tid >> 6;
  const int rr = lane & 15, gq = lane >> 4;
  const int mtile = blockIdx.y * 16;
  const int ncol = blockIdx.x * 64 + wave * 16;
  const int row = mtile + rr;

  f32x4 a4 = (f32x4){0.f, 0.f, 0.f, 0.f};
#pragma unroll
  for (int ks2 = 0; ks2 < 16; ++ks2) {
    const int k0 = ks2 * 32 + gq * 8;
    float4 x0 = *(const float4*)&acc[(size_t)row * HD + k0];
    float4 x1 = *(const float4*)&acc[(size_t)row * HD + k0 + 4];
    float4 b0 = *(const float4*)&bstem[k0];
    float4 b1 = *(const float4*)&bstem[k0 + 4];
    bf16x8 af;
    af[0] = (short)bfc(fmaxf(x0.x + b0.x, 0.f));
    af[1] = (short)bfc(fmaxf(x0.y + b0.y, 0.f));
    af[2] = (short)bfc(fmaxf(x0.z + b0.z, 0.f));
    af[3] = (short)bfc(fmaxf(x0.w + b0.w, 0.f));
    af[4] = (short)bfc(fmaxf(x1.x + b1.x, 0.f));
    af[5] = (short)bfc(fmaxf(x1.y + b1.y, 0.f));
    af[6] = (short)bfc(fmaxf(x1.z + b1.z, 0.f));
    af[7] = (short)bfc(fmaxf(x1.w + b1.w, 0.f));
    bf16x8 bf = *(const bf16x8*)&WcT[(size_t)(ncol + rr) * 512 + k0];
    a4 = __builtin_amdgcn_mfma_f32_16x16x32_bf16(af, bf, a4, 0, 0, 0);
  }
  const int col = ncol + rr;
  if (col < 512) {
    const float bb = bq[col];
#pragma unroll
    for (int i = 0; i < 4; ++i)
      hfqg[(size_t)(mtile + 4 * gq + i) * HD + col] = a4[i] + bb;
  } else {
    const float bb = bg[col - 512];
#pragma unroll
    for (int i = 0; i < 4; ++i)
      enc0g[(size_t)(mtile + 4 * gq + i) * 128 + (col - 512)] = a4[i] + bb;
  }
}

// ---------------- Recurrent scan: one block (512 thr) per batch row ----------------
// Reads PRE-PACKED bf16 weights (halves global traffic vs f32 + packing in-kernel).
__global__ __launch_bounds__(512, 2)
void scan_kernel(const float* __restrict__ hfqg, const float* __restrict__ enc0g,
                 const uint* __restrict__ wzqg, const uint* __restrict__ wzpg,
                 const uint* __restrict__ wlqg, const uint* __restrict__ wlpg,
                 const float* __restrict__ blinq, const float* __restrict__ blinp,
                 const float* __restrict__ bp,
                 const float* __restrict__ eps0, const float* __restrict__ epsq,
                 ushort* __restrict__ zsb, float* __restrict__ out_kl) {
  const int b = blockIdx.x, tid = threadIdx.x;
  __shared__ uint WlL[2][64 * 128];
  __shared__ float g[512], gp[512];
  __shared__ float hq[128], hp[128];
  __shared__ float psum[512];
  __shared__ float zsh[64];
  __shared__ float epsL[448];

  uint wq[32], wp[32];
#pragma unroll
  for (int zp = 0; zp < 32; ++zp) {
    wq[zp] = wzqg[zp * 512 + tid];
    wp[zp] = wzpg[zp * 512 + tid];
  }
#pragma unroll
  for (int i = 0; i < 16; ++i) {
    const int idx = i * 512 + tid;
    WlL[0][idx] = wlqg[idx];
    WlL[1][idx] = wlpg[idx];
  }
  if (tid < 448) epsL[tid] = epsq[(size_t)((tid >> 6) * NB + b) * ZD + (tid & 63)];
  const float hfq_reg = hfqg[(size_t)b * HD + tid];
  const float bp_reg = bp[tid];
  if (tid < 64) {
    float mu = enc0g[b * 128 + tid], lv = enc0g[b * 128 + 64 + tid];
    float s0 = softplusf_(lv + 0.5f) + 1e-8f;
    float z0 = mu + s0 * eps0[b * ZD + tid];
    zsh[tid] = z0;
    zsb[(b * KS) * ZD + tid] = bfc(z0);
    out_kl[(b * ZD + tid) * KS] = -logf(s0) + (s0 * s0 + mu * mu) * 0.5f - 0.5f;
  }
  __syncthreads();

  for (int t = 0; t < KS - 1; ++t) {
    float aq = hfq_reg, ap = bp_reg;
#pragma unroll
    for (int zp = 0; zp < 32; ++zp) {
      float z0v = zsh[2 * zp], z1v = zsh[2 * zp + 1];
      uint uq = wq[zp], up = wp[zp];
      aq += z0v * lof(uq) + z1v * hif(uq);
      ap += z0v * lof(up) + z1v * hif(up);
    }
    g[tid] = aq;
    gp[tid] = ap;
    __syncthreads();
    if (tid < 128) {
      float cs = sigmoidf_(g[tid]) * tanhf(g[256 + tid]);
      hq[tid] = sigmoidf_(g[384 + tid]) * tanhf(cs);
    } else if (tid < 256) {
      int j = tid & 127;
      float cs = sigmoidf_(gp[j]) * tanhf(gp[256 + j]);
      hp[j] = sigmoidf_(gp[384 + j]) * tanhf(cs);
    }
    __syncthreads();
    {
      int s = tid & 255, jj = s & 127, kc = s >> 7;
      int mq_ = tid >> 8;
      const float* h = mq_ ? hp : hq;
      const uint* W = WlL[mq_];
      float a = 0.f;
#pragma unroll
      for (int kp = 0; kp < 32; ++kp) {
        uint u = W[(kc * 32 + kp) * 128 + jj];
        a += h[kc * 64 + 2 * kp] * lof(u) + h[kc * 64 + 2 * kp + 1] * hif(u);
      }
      psum[tid] = a;
    }
    __syncthreads();
    if (tid < 64) {
      float mq = psum[tid] + psum[128 + tid] + blinq[tid];
      float lq = psum[64 + tid] + psum[192 + tid] + blinq[64 + tid];
      float sq = softplusf_(lq + 0.5f) + 1e-8f;
      float zq = mq + sq * epsL[t * 64 + tid];
      float mp2 = psum[256 + tid] + psum[384 + tid] + blinp[tid];
      float lp = psum[320 + tid] + psum[448 + tid] + blinp[64 + tid];
      float sp_ = softplusf_(lp + 0.5f) + 1e-8f;
      float d = mq - mp2;
      out_kl[(b * ZD + tid) * KS + t + 1] =
          logf(sp_ / sq) + (sq * sq + d * d) / (2.f * sp_ * sp_) - 0.5f;
      zsb[(b * KS + t + 1) * ZD + tid] = bfc(zq);
      zsh[tid] = zq;
    }
    __syncthreads();
  }
}

// -------- Decoder: MFMA + log-sigmoid + excl k-cumsum. 2 m-tiles/block, ILP-hoisted --------
__global__ __launch_bounds__(256)
void dec_kernel(const ushort* __restrict__ zsb, const ushort* __restrict__ WdT,
                const float* __restrict__ bd, float* __restrict__ out) {
  const int tid = threadIdx.x;
  const int lane = tid & 63;
  const int wave = tid >> 6;
  const int rr = lane & 15, gq = lane >> 4;
  const int mtile0 = blockIdx.y * 32;              // 2048/32 = 64
  const int ncol0 = blockIdx.x * 256 + wave * 64;  // 16384/256 = 64

  bf16x8 bfr[2][4];
#pragma unroll
  for (int ks2 = 0; ks2 < 2; ++ks2)
#pragma unroll
    for (int nf = 0; nf < 4; ++nf)
      bfr[ks2][nf] = *(const bf16x8*)&WdT[(size_t)(ncol0 + nf * 16 + rr) * 64 +
                                          ks2 * 32 + gq * 8];
  bf16x8 af[2][2];
#pragma unroll
  for (int mi = 0; mi < 2; ++mi)
#pragma unroll
    for (int ks2 = 0; ks2 < 2; ++ks2)
      af[mi][ks2] = *(const bf16x8*)&zsb[(size_t)(mtile0 + mi * 16 + rr) * 64 +
                                         ks2 * 32 + gq * 8];
  float bde[4];
#pragma unroll
  for (int nf = 0; nf < 4; ++nf) bde[nf] = bd[ncol0 + nf * 16 + rr];

  f32x4 acc[2][4];
#pragma unroll
  for (int mi = 0; mi < 2; ++mi)
#pragma unroll
    for (int nf = 0; nf < 4; ++nf) acc[mi][nf] = (f32x4){0.f, 0.f, 0.f, 0.f};

#pragma unroll
  for (int mi = 0; mi < 2; ++mi)
#pragma unroll
    for (int ks2 = 0; ks2 < 2; ++ks2)
#pragma unroll
      for (int nf = 0; nf < 4; ++nf)
        acc[mi][nf] = __builtin_amdgcn_mfma_f32_16x16x32_bf16(
            af[mi][ks2], bfr[ks2][nf], acc[mi][nf], 0, 0, 0);

  const int khi = (gq & 1) * 4;
#pragma unroll
  for (int mi = 0; mi < 2; ++mi) {
    const int bb = ((mtile0 + mi * 16) >> 3) + (gq >> 1);
#pragma unroll
    for (int nf = 0; nf < 4; ++nf) {
      const int col = ncol0 + nf * 16 + rr;
      float run = 0.f;
      float ov[4];
#pragma unroll
      for (int i = 0; i < 4; ++i) {
        float dec = acc[mi][nf][i] + bde[nf];
        float spd = softplus_fast(dec);
        ov[i] = run + (dec - spd);
        run -= spd;
      }
      float prev = __shfl_xor(run, 16, 64);
      float base = (gq & 1) ? prev : 0.f;
#pragma unroll
      for (int i = 0; i < 4; ++i)
        out[((size_t)(khi + i) * NB + bb) * DN + col] = ov[i] + base;
    }
  }
}

extern "C" void kernel_launch(void* const* d_in, const int* in_sizes, int n_in,
                              void* d_out, int out_size, void* d_ws, size_t ws_size,
                              hipStream_t stream) {
  (void)in_sizes; (void)n_in; (void)out_size; (void)ws_size;
  const float* x     = (const float*)d_in[0];
  const float* eps0  = (const float*)d_in[2];
  const float* epsq  = (const float*)d_in[3];
  const float* Wstem = (const float*)d_in[5];
  const float* bstem = (const float*)d_in[6];
  const float* Wg    = (const float*)d_in[7];
  const float* bgp   = (const float*)d_in[8];
  const float* Wihq  = (const float*)d_in[9];
  const float* bq    = (const float*)d_in[10];
  const float* Wlinq = (const float*)d_in[11];
  const float* blinq = (const float*)d_in[12];
  const float* Wihp  = (const float*)d_in[13];
  const float* bp    = (const float*)d_in[14];
  const float* Wlinp = (const float*)d_in[15];
  const float* blinp = (const float*)d_in[16];
  const float* Wd    = (const float*)d_in[17];
  const float* bd    = (const float*)d_in[18];

  float* out    = (float*)d_out;
  float* outkl  = out + (size_t)KS * NB * DN;
  float* accbuf = (float*)d_ws;                        // 512 KB
  ushort* zsb   = (ushort*)(accbuf + NB * HD);         // 256 KB
  ushort* wdt   = zsb + (size_t)KS * NB * ZD;          // 2 MB
  ushort* wcombT = wdt + (size_t)DN * ZD;              // 640 KB
  float* hfqg   = (float*)(wcombT + 640 * 512);        // 512 KB
  float* enc0g  = hfqg + NB * HD;                      // 128 KB
  uint* wzq     = (uint*)(enc0g + NB * 128);           // 64 KB
  uint* wzp     = wzq + 32 * 512;                      // 64 KB
  uint* wlq     = wzp + 32 * 512;                      // 32 KB
  uint* wlp     = wlq + 64 * 128;                      // 32 KB
  // split-K partials live in d_out's log_ms region (134 MB, dead until dec runs):
  float* part   = out;  // 128 * 256*512 f32 = 64 MB

  prep_kernel<<<160, 256, 0, stream>>>(Wd, wdt, Wihq, Wg, wcombT, Wihp,
                                       Wlinq, Wlinp, wzq, wzp, wlq, wlp);
  stem_kernel<<<4 * SPLITS, 256, 0, stream>>>(x, Wstem, part);
  reduce_kernel<<<NB * HD / 4 / 128, 256, 0, stream>>>(part, accbuf);
  gemmA_kernel<<<dim3(10, 16), 256, 0, stream>>>(accbuf, bstem, wcombT, bq, bgp,
                                                 hfqg, enc0g);
  scan_kernel<<<NB, 512, 0, stream>>>(hfqg, enc0g, wzq, wzp, wlq, wlp,
                                      blinq, blinp, bp, eps0, epsq, zsb, outkl);
  dec_kernel<<<dim3(64, 64), 256, 0, stream>>>(zsb, wdt, bd, out);
}

// Round 14
// 120.877 us; speedup vs baseline: 1.1959x; 1.0934x over previous
//
#include <hip/hip_runtime.h>
#include <hip/hip_bf16.h>

#define ZD 64
#define HD 512
#define NB 256
#define KS 8
#define DIN 49152
#define DN 16384

typedef __attribute__((ext_vector_type(8))) short bf16x8;
typedef __attribute__((ext_vector_type(4))) float f32x4;

__device__ __forceinline__ ushort bfc(float x) {
  uint u = __float_as_uint(x);
  uint r = (u + 0x7FFFu + ((u >> 16) & 1u)) >> 16;
  return (ushort)r;
}
__device__ __forceinline__ uint pk2(float a, float b) {
  return (uint)bfc(a) | ((uint)bfc(b) << 16);
}
// HW packed f32->bf16 RTNE (T12 recipe; no builtin on gfx950)
__device__ __forceinline__ uint cvtpk(float lo, float hi) {
  uint r;
  asm("v_cvt_pk_bf16_f32 %0, %1, %2" : "=v"(r) : "v"(lo), "v"(hi));
  return r;
}
__device__ __forceinline__ float lof(uint u) { return __uint_as_float(u << 16); }
__device__ __forceinline__ float hif(uint u) { return __uint_as_float(u & 0xFFFF0000u); }
__device__ __forceinline__ float bf2f(ushort u) { return __uint_as_float((uint)u << 16); }
__device__ __forceinline__ float softplusf_(float x) {
  return fmaxf(x, 0.f) + log1pf(expf(-fabsf(x)));
}
__device__ __forceinline__ float softplus_fast(float x) {
  float e = __expf(-fabsf(x));
  return fmaxf(x, 0.f) + __logf(1.f + e);
}
__device__ __forceinline__ float sigmoidf_(float x) {
  return 1.f / (1.f + expf(-x));
}

// ---------------- FUSED stem (blocks 0..511) + prep (blocks 512..671) ----------------
// Stem: BM=256 (W read once), BN=128, BKK=32 (12 K-steps), SPLITS=128.
// Partials stored BF16 (halves partial write+read traffic).
// Prep (independent of stem; consumed only by later launches) rides along and
// hides under the stem's fabric-bound phase.
#define SPLITS 128
#define KCH (DIN / SPLITS) /* 384 */
#define BKK 32

__global__ __launch_bounds__(256, 2)
void stem_prep_kernel(const float* __restrict__ x, const float* __restrict__ W,
                      ushort* __restrict__ part,
                      const float* __restrict__ Wd, ushort* __restrict__ WdT,
                      const float* __restrict__ Wihq, const float* __restrict__ Wg,
                      ushort* __restrict__ WcT, const float* __restrict__ Wihp,
                      const float* __restrict__ Wlinq, const float* __restrict__ Wlinp,
                      uint* __restrict__ wzq, uint* __restrict__ wzp,
                      uint* __restrict__ wlq, uint* __restrict__ wlp) {
  __shared__ float Af[256 * 32];  // 32 KB f32 [row][slot16], slot16 = logical ^ (row&7)
  __shared__ uint Bt[128 * 20];   // 10 KB [n][16 u32 + 4 pad], granule-rotated
  __shared__ float T[64][68];     // prep transpose buffer
  const int tid = threadIdx.x;

  if (blockIdx.x >= 512) {  // ================= PREP ROLE =================
    const int bx = blockIdx.x - 512;
    const int t = tid;
    if (bx < 64) {  // WdT[col*64+k] = bf16(Wd[k*DN+col])
      const int c = bx * 256 + t;
      uint packed[32];
#pragma unroll
      for (int k = 0; k < 32; ++k) {
        float a = Wd[(size_t)(2 * k) * DN + c];
        float b = Wd[(size_t)(2 * k + 1) * DN + c];
        packed[k] = pk2(a, b);
      }
      uint4* dst = (uint4*)&WdT[(size_t)c * 64];
#pragma unroll
      for (int i = 0; i < 8; ++i)
        dst[i] = make_uint4(packed[4 * i], packed[4 * i + 1], packed[4 * i + 2],
                            packed[4 * i + 3]);
    } else if (bx < 144) {  // WcombT: bf16 [640 cols][512 k] of [Wihq[:512] | Wg]
      const int bx2 = bx - 64;
      const int cx = bx2 % 10, ky = bx2 / 10;
      const int ct = cx * 64, kt = ky * 64;
      {
        const int rl = t >> 2, cq = (t & 3) * 16;
        const float* src = (cx < 8) ? &Wihq[(size_t)(kt + rl) * 512 + ct + cq]
                                    : &Wg[(size_t)(kt + rl) * 128 + (ct - 512) + cq];
#pragma unroll
        for (int i = 0; i < 4; ++i) {
          float4 v = *(const float4*)(src + 4 * i);
          T[rl][cq + 4 * i + 0] = v.x;
          T[rl][cq + 4 * i + 1] = v.y;
          T[rl][cq + 4 * i + 2] = v.z;
          T[rl][cq + 4 * i + 3] = v.w;
        }
      }
      __syncthreads();
      {
        const int cl = t >> 2, kq = (t & 3) * 16;
        uint* dst = (uint*)WcT;
#pragma unroll
        for (int i = 0; i < 8; ++i) {
          uint u = pk2(T[kq + 2 * i][cl], T[kq + 2 * i + 1][cl]);
          dst[(((size_t)(ct + cl)) * 512 + kt + kq + 2 * i) >> 1] = u;
        }
      }
    } else {  // pack scan weights to bf16 pairs
      const int tp = (bx - 144) * 256 + t;  // 0..4095
#pragma unroll
      for (int r2 = 0; r2 < 4; ++r2) {
        const int i = tp * 4 + r2;          // 0..16383
        const int zp = i >> 9, col = i & 511;
        wzq[i] = pk2(Wihq[(size_t)(HD + 2 * zp) * HD + col],
                     Wihq[(size_t)(HD + 2 * zp + 1) * HD + col]);
        wzp[i] = pk2(Wihp[(size_t)(2 * zp) * HD + col],
                     Wihp[(size_t)(2 * zp + 1) * HD + col]);
        if (i < 8192) {
          const int kp2 = i >> 7, jj = i & 127;
          wlq[i] = pk2(Wlinq[(2 * kp2) * 128 + jj], Wlinq[(2 * kp2 + 1) * 128 + jj]);
          wlp[i] = pk2(Wlinp[(2 * kp2) * 128 + jj], Wlinp[(2 * kp2 + 1) * 128 + jj]);
        }
      }
    }
    return;
  }

  // ================= STEM ROLE (R13-validated structure) =================
  const int id = blockIdx.x;                       // 0..511
  const int nt = (id >> 3) & 3;                    // n-tile 0..3
  const int sp = (id >> 5) * 8 + (id & 7);         // 0..127 (bijective)
  const int n0 = nt * 128;
  const int lane = tid & 63;
  const int wave = tid >> 6;                 // 4 waves
  const int wm = wave >> 1, wn = wave & 1;   // wave tile: 128 x 64
  const int rr = lane & 15, gq = lane >> 4;

  f32x4 accr[8][4];
#pragma unroll
  for (int i = 0; i < 8; ++i)
#pragma unroll
    for (int j = 0; j < 4; ++j) accr[i][j] = (f32x4){0.f, 0.f, 0.f, 0.f};

  const int arow_b = tid >> 3;   // A: 8 thr/row; + 32*i per instr
  const int asub = tid & 7;      // 16B slot within 128B row-chunk
  const int bkq = tid >> 5, bn4 = tid & 31;  // B: k-quad, n-quad
  auto* ldsA = (__attribute__((address_space(3))) uint*)Af;

#pragma unroll 1
  for (int it = 0; it < KCH / BKK; ++it) {
    const int k0 = sp * KCH + it * BKK;
    __syncthreads();  // previous compute done; LDS safe to overwrite
#pragma unroll
    for (int i = 0; i < 8; ++i) {
      const int row = i * 32 + arow_b;
      const int slot = asub ^ (row & 7);
      const float* g = x + (size_t)row * DIN + k0 + slot * 4;
      __builtin_amdgcn_global_load_lds(
          (const __attribute__((address_space(1))) uint*)g,
          ldsA + i * 1024 + wave * 256, 16, 0, 0);
    }
    {
      float4 vb[4];
#pragma unroll
      for (int j = 0; j < 4; ++j)
        vb[j] = *(const float4*)(W + (size_t)(k0 + bkq * 4 + j) * HD + n0 + bn4 * 4);
      const int gg = bkq >> 1, sb = bkq & 1;
#pragma unroll
      for (int c = 0; c < 4; ++c) {
        const int n = bn4 * 4 + c;
        const float* q0 = (const float*)&vb[0];
        const float* q1 = (const float*)&vb[1];
        const float* q2 = (const float*)&vb[2];
        const float* q3 = (const float*)&vb[3];
        uint lo = cvtpk(q0[c], q1[c]);
        uint hi = cvtpk(q2[c], q3[c]);
        const int rot = (gg + (n >> 2) + n) & 3;
        *(uint2*)&Bt[n * 20 + rot * 4 + sb * 2] = make_uint2(lo, hi);
      }
    }
    asm volatile("s_waitcnt vmcnt(0)" ::: "memory");
    __syncthreads();  // all staging (gload_lds + ds_writes) visible
    bf16x8 af[8], bfr[4];
#pragma unroll
    for (int mf = 0; mf < 8; ++mf) {
      const int r = wm * 128 + mf * 16 + rr;
      const int s = r & 7;
      float4 a0 = *(const float4*)&Af[r * 32 + ((gq * 2) ^ s) * 4];
      float4 a1 = *(const float4*)&Af[r * 32 + ((gq * 2 + 1) ^ s) * 4];
      uint4 au = make_uint4(cvtpk(a0.x, a0.y), cvtpk(a0.z, a0.w),
                            cvtpk(a1.x, a1.y), cvtpk(a1.z, a1.w));
      af[mf] = *(bf16x8*)&au;
    }
#pragma unroll
    for (int nf = 0; nf < 4; ++nf) {
      const int n = wn * 64 + nf * 16 + rr;
      const int rot = (gq + (n >> 2) + n) & 3;
      uint4 bu = *(const uint4*)&Bt[n * 20 + rot * 4];
      bfr[nf] = *(bf16x8*)&bu;
    }
#pragma unroll
    for (int mf = 0; mf < 8; ++mf)
#pragma unroll
      for (int nf = 0; nf < 4; ++nf)
        accr[mf][nf] = __builtin_amdgcn_mfma_f32_16x16x32_bf16(
            af[mf], bfr[nf], accr[mf][nf], 0, 0, 0);
  }

  // C/D layout: col = lane&15, row = 4*(lane>>4)+i ; bf16 partial stores
  const int ccol = lane & 15, crow = (lane >> 4) * 4;
  ushort* base = part + (size_t)sp * (NB * HD);
#pragma unroll
  for (int mf = 0; mf < 8; ++mf) {
#pragma unroll
    for (int nf = 0; nf < 4; ++nf) {
      const int col = n0 + wn * 64 + nf * 16 + ccol;
      const int row = wm * 128 + mf * 16 + crow;
#pragma unroll
      for (int i = 0; i < 4; ++i)
        base[(size_t)(row + i) * HD + col] = bfc(accr[mf][nf][i]);
    }
  }
}

// ---- Stem stage 2: acc = sum over 128 bf16 partials; 2 threads/output ----
__global__ __launch_bounds__(256)
void reduce_kernel(const ushort* __restrict__ part, float* __restrict__ acc) {
  __shared__ float4 sh[128];
  const int q4 = blockIdx.x * 128 + (threadIdx.x & 127);  // ushort4 idx, 32768 total
  const int half = threadIdx.x >> 7;                      // 0 or 1
  const ushort4* p = (const ushort4*)part;
  float4 s = {0.f, 0.f, 0.f, 0.f};
#pragma unroll 8
  for (int sp = half * 64; sp < half * 64 + 64; ++sp) {
    ushort4 v = p[(size_t)sp * (NB * HD / 4) + q4];
    s.x += bf2f(v.x); s.y += bf2f(v.y); s.z += bf2f(v.z); s.w += bf2f(v.w);
  }
  if (half) sh[threadIdx.x - 128] = s;
  __syncthreads();
  if (!half) {
    float4 o = sh[threadIdx.x];
    o.x += s.x; o.y += s.y; o.z += s.z; o.w += s.w;
    ((float4*)acc)[q4] = o;
  }
}

// ---- gemmA: hf = relu(acc+bstem); hfqg = hf@Wihq[:512]+bq ; enc0g = hf@Wg+bg ----
__global__ __launch_bounds__(256)
void gemmA_kernel(const float* __restrict__ acc, const float* __restrict__ bstem,
                  const ushort* __restrict__ WcT, const float* __restrict__ bq,
                  const float* __restrict__ bg, float* __restrict__ hfqg,
                  float* __restrict__ enc0g) {
  const int tid = threadIdx.x;
  const int lane = tid & 63;
  const int wave = tid >> 6;
  const int rr = lane & 15, gq = lane >> 4;
  const int mtile = blockIdx.y * 16;
  const int ncol = blockIdx.x * 64 + wave * 16;
  const int row = mtile + rr;

  f32x4 a4 = (f32x4){0.f, 0.f, 0.f, 0.f};
#pragma unroll
  for (int ks2 = 0; ks2 < 16; ++ks2) {
    const int k0 = ks2 * 32 + gq * 8;
    float4 x0 = *(const float4*)&acc[(size_t)row * HD + k0];
    float4 x1 = *(const float4*)&acc[(size_t)row * HD + k0 + 4];
    float4 b0 = *(const float4*)&bstem[k0];
    float4 b1 = *(const float4*)&bstem[k0 + 4];
    bf16x8 af;
    af[0] = (short)bfc(fmaxf(x0.x + b0.x, 0.f));
    af[1] = (short)bfc(fmaxf(x0.y + b0.y, 0.f));
    af[2] = (short)bfc(fmaxf(x0.z + b0.z, 0.f));
    af[3] = (short)bfc(fmaxf(x0.w + b0.w, 0.f));
    af[4] = (short)bfc(fmaxf(x1.x + b1.x, 0.f));
    af[5] = (short)bfc(fmaxf(x1.y + b1.y, 0.f));
    af[6] = (short)bfc(fmaxf(x1.z + b1.z, 0.f));
    af[7] = (short)bfc(fmaxf(x1.w + b1.w, 0.f));
    bf16x8 bf = *(const bf16x8*)&WcT[(size_t)(ncol + rr) * 512 + k0];
    a4 = __builtin_amdgcn_mfma_f32_16x16x32_bf16(af, bf, a4, 0, 0, 0);
  }
  const int col = ncol + rr;
  if (col < 512) {
    const float bb = bq[col];
#pragma unroll
    for (int i = 0; i < 4; ++i)
      hfqg[(size_t)(mtile + 4 * gq + i) * HD + col] = a4[i] + bb;
  } else {
    const float bb = bg[col - 512];
#pragma unroll
    for (int i = 0; i < 4; ++i)
      enc0g[(size_t)(mtile + 4 * gq + i) * 128 + (col - 512)] = a4[i] + bb;
  }
}

// ---------------- Recurrent scan: one block (512 thr) per batch row ----------------
__global__ __launch_bounds__(512, 2)
void scan_kernel(const float* __restrict__ hfqg, const float* __restrict__ enc0g,
                 const uint* __restrict__ wzqg, const uint* __restrict__ wzpg,
                 const uint* __restrict__ wlqg, const uint* __restrict__ wlpg,
                 const float* __restrict__ blinq, const float* __restrict__ blinp,
                 const float* __restrict__ bp,
                 const float* __restrict__ eps0, const float* __restrict__ epsq,
                 ushort* __restrict__ zsb, float* __restrict__ out_kl) {
  const int b = blockIdx.x, tid = threadIdx.x;
  __shared__ uint WlL[2][64 * 128];
  __shared__ float g[512], gp[512];
  __shared__ float hq[128], hp[128];
  __shared__ float psum[512];
  __shared__ float zsh[64];
  __shared__ float epsL[448];

  uint wq[32], wp[32];
#pragma unroll
  for (int zp = 0; zp < 32; ++zp) {
    wq[zp] = wzqg[zp * 512 + tid];
    wp[zp] = wzpg[zp * 512 + tid];
  }
#pragma unroll
  for (int i = 0; i < 16; ++i) {
    const int idx = i * 512 + tid;
    WlL[0][idx] = wlqg[idx];
    WlL[1][idx] = wlpg[idx];
  }
  if (tid < 448) epsL[tid] = epsq[(size_t)((tid >> 6) * NB + b) * ZD + (tid & 63)];
  const float hfq_reg = hfqg[(size_t)b * HD + tid];
  const float bp_reg = bp[tid];
  if (tid < 64) {
    float mu = enc0g[b * 128 + tid], lv = enc0g[b * 128 + 64 + tid];
    float s0 = softplusf_(lv + 0.5f) + 1e-8f;
    float z0 = mu + s0 * eps0[b * ZD + tid];
    zsh[tid] = z0;
    zsb[(b * KS) * ZD + tid] = bfc(z0);
    out_kl[(b * ZD + tid) * KS] = -logf(s0) + (s0 * s0 + mu * mu) * 0.5f - 0.5f;
  }
  __syncthreads();

  for (int t = 0; t < KS - 1; ++t) {
    float aq = hfq_reg, ap = bp_reg;
#pragma unroll
    for (int zp = 0; zp < 32; ++zp) {
      float z0v = zsh[2 * zp], z1v = zsh[2 * zp + 1];
      uint uq = wq[zp], up = wp[zp];
      aq += z0v * lof(uq) + z1v * hif(uq);
      ap += z0v * lof(up) + z1v * hif(up);
    }
    g[tid] = aq;
    gp[tid] = ap;
    __syncthreads();
    if (tid < 128) {
      float cs = sigmoidf_(g[tid]) * tanhf(g[256 + tid]);
      hq[tid] = sigmoidf_(g[384 + tid]) * tanhf(cs);
    } else if (tid < 256) {
      int j = tid & 127;
      float cs = sigmoidf_(gp[j]) * tanhf(gp[256 + j]);
      hp[j] = sigmoidf_(gp[384 + j]) * tanhf(cs);
    }
    __syncthreads();
    {
      int s = tid & 255, jj = s & 127, kc = s >> 7;
      int mq_ = tid >> 8;
      const float* h = mq_ ? hp : hq;
      const uint* W = WlL[mq_];
      float a = 0.f;
#pragma unroll
      for (int kp = 0; kp < 32; ++kp) {
        uint u = W[(kc * 32 + kp) * 128 + jj];
        a += h[kc * 64 + 2 * kp] * lof(u) + h[kc * 64 + 2 * kp + 1] * hif(u);
      }
      psum[tid] = a;
    }
    __syncthreads();
    if (tid < 64) {
      float mq = psum[tid] + psum[128 + tid] + blinq[tid];
      float lq = psum[64 + tid] + psum[192 + tid] + blinq[64 + tid];
      float sq = softplusf_(lq + 0.5f) + 1e-8f;
      float zq = mq + sq * epsL[t * 64 + tid];
      float mp2 = psum[256 + tid] + psum[384 + tid] + blinp[tid];
      float lp = psum[320 + tid] + psum[448 + tid] + blinp[64 + tid];
      float sp_ = softplusf_(lp + 0.5f) + 1e-8f;
      float d = mq - mp2;
      out_kl[(b * ZD + tid) * KS + t + 1] =
          logf(sp_ / sq) + (sq * sq + d * d) / (2.f * sp_ * sp_) - 0.5f;
      zsb[(b * KS + t + 1) * ZD + tid] = bfc(zq);
      zsh[tid] = zq;
    }
    __syncthreads();
  }
}

// -------- Decoder: MFMA + log-sigmoid + excl k-cumsum. 2 m-tiles/block, ILP-hoisted --------
__global__ __launch_bounds__(256)
void dec_kernel(const ushort* __restrict__ zsb, const ushort* __restrict__ WdT,
                const float* __restrict__ bd, float* __restrict__ out) {
  const int tid = threadIdx.x;
  const int lane = tid & 63;
  const int wave = tid >> 6;
  const int rr = lane & 15, gq = lane >> 4;
  const int mtile0 = blockIdx.y * 32;              // 2048/32 = 64
  const int ncol0 = blockIdx.x * 256 + wave * 64;  // 16384/256 = 64

  bf16x8 bfr[2][4];
#pragma unroll
  for (int ks2 = 0; ks2 < 2; ++ks2)
#pragma unroll
    for (int nf = 0; nf < 4; ++nf)
      bfr[ks2][nf] = *(const bf16x8*)&WdT[(size_t)(ncol0 + nf * 16 + rr) * 64 +
                                          ks2 * 32 + gq * 8];
  bf16x8 af[2][2];
#pragma unroll
  for (int mi = 0; mi < 2; ++mi)
#pragma unroll
    for (int ks2 = 0; ks2 < 2; ++ks2)
      af[mi][ks2] = *(const bf16x8*)&zsb[(size_t)(mtile0 + mi * 16 + rr) * 64 +
                                         ks2 * 32 + gq * 8];
  float bde[4];
#pragma unroll
  for (int nf = 0; nf < 4; ++nf) bde[nf] = bd[ncol0 + nf * 16 + rr];

  f32x4 acc[2][4];
#pragma unroll
  for (int mi = 0; mi < 2; ++mi)
#pragma unroll
    for (int nf = 0; nf < 4; ++nf) acc[mi][nf] = (f32x4){0.f, 0.f, 0.f, 0.f};

#pragma unroll
  for (int mi = 0; mi < 2; ++mi)
#pragma unroll
    for (int ks2 = 0; ks2 < 2; ++ks2)
#pragma unroll
      for (int nf = 0; nf < 4; ++nf)
        acc[mi][nf] = __builtin_amdgcn_mfma_f32_16x16x32_bf16(
            af[mi][ks2], bfr[ks2][nf], acc[mi][nf], 0, 0, 0);

  const int khi = (gq & 1) * 4;
#pragma unroll
  for (int mi = 0; mi < 2; ++mi) {
    const int bb = ((mtile0 + mi * 16) >> 3) + (gq >> 1);
#pragma unroll
    for (int nf = 0; nf < 4; ++nf) {
      const int col = ncol0 + nf * 16 + rr;
      float run = 0.f;
      float ov[4];
#pragma unroll
      for (int i = 0; i < 4; ++i) {
        float dec = acc[mi][nf][i] + bde[nf];
        float spd = softplus_fast(dec);
        ov[i] = run + (dec - spd);
        run -= spd;
      }
      float prev = __shfl_xor(run, 16, 64);
      float base = (gq & 1) ? prev : 0.f;
#pragma unroll
      for (int i = 0; i < 4; ++i)
        out[((size_t)(khi + i) * NB + bb) * DN + col] = ov[i] + base;
    }
  }
}

extern "C" void kernel_launch(void* const* d_in, const int* in_sizes, int n_in,
                              void* d_out, int out_size, void* d_ws, size_t ws_size,
                              hipStream_t stream) {
  (void)in_sizes; (void)n_in; (void)out_size; (void)ws_size;
  const float* x     = (const float*)d_in[0];
  const float* eps0  = (const float*)d_in[2];
  const float* epsq  = (const float*)d_in[3];
  const float* Wstem = (const float*)d_in[5];
  const float* bstem = (const float*)d_in[6];
  const float* Wg    = (const float*)d_in[7];
  const float* bgp   = (const float*)d_in[8];
  const float* Wihq  = (const float*)d_in[9];
  const float* bq    = (const float*)d_in[10];
  const float* Wlinq = (const float*)d_in[11];
  const float* blinq = (const float*)d_in[12];
  const float* Wihp  = (const float*)d_in[13];
  const float* bp    = (const float*)d_in[14];
  const float* Wlinp = (const float*)d_in[15];
  const float* blinp = (const float*)d_in[16];
  const float* Wd    = (const float*)d_in[17];
  const float* bd    = (const float*)d_in[18];

  float* out    = (float*)d_out;
  float* outkl  = out + (size_t)KS * NB * DN;
  float* accbuf = (float*)d_ws;                        // 512 KB
  ushort* zsb   = (ushort*)(accbuf + NB * HD);         // 256 KB
  ushort* wdt   = zsb + (size_t)KS * NB * ZD;          // 2 MB
  ushort* wcombT = wdt + (size_t)DN * ZD;              // 640 KB
  float* hfqg   = (float*)(wcombT + 640 * 512);        // 512 KB
  float* enc0g  = hfqg + NB * HD;                      // 128 KB
  uint* wzq     = (uint*)(enc0g + NB * 128);           // 64 KB
  uint* wzp     = wzq + 32 * 512;                      // 64 KB
  uint* wlq     = wzp + 32 * 512;                      // 32 KB
  uint* wlp     = wlq + 64 * 128;                      // 32 KB
  // bf16 split-K partials live in d_out's log_ms region (dead until dec runs):
  ushort* part  = (ushort*)out;  // 128 * 256*512 bf16 = 32 MB

  stem_prep_kernel<<<4 * SPLITS + 160, 256, 0, stream>>>(
      x, Wstem, part, Wd, wdt, Wihq, Wg, wcombT, Wihp, Wlinq, Wlinp,
      wzq, wzp, wlq, wlp);
  reduce_kernel<<<NB * HD / 4 / 128, 256, 0, stream>>>(part, accbuf);
  gemmA_kernel<<<dim3(10, 16), 256, 0, stream>>>(accbuf, bstem, wcombT, bq, bgp,
                                                 hfqg, enc0g);
  scan_kernel<<<NB, 512, 0, stream>>>(hfqg, enc0g, wzq, wzp, wlq, wlp,
                                      blinq, blinp, bp, eps0, epsq, zsb, outkl);
  dec_kernel<<<dim3(64, 64), 256, 0, stream>>>(zsb, wdt, bd, out);
}